// Round 10
// baseline (316.095 us; speedup 1.0000x reference)
//
#include <hip/hip_runtime.h>
#include <hip/hip_bf16.h>
#include <hip/hip_cooperative_groups.h>

namespace cg = cooperative_groups;

#define NN 8192
#define INC 256
#define OUTC 512
#define NE 262144
#define MAXD 128
#define JC 4
#define JLEN 128  // OUTC / JC

typedef __hip_bfloat16 bf16;
typedef short bf16x8 __attribute__((ext_vector_type(8)));
typedef float f32x16 __attribute__((ext_vector_type(16)));

__device__ inline unsigned short f2bu(float f) {
  __hip_bfloat16 b = __float2bfloat16(f);
  return *reinterpret_cast<unsigned short*>(&b);
}
__device__ inline float blo(unsigned int x) { return __uint_as_float(x << 16); }
__device__ inline float bhi(unsigned int x) { return __uint_as_float(x & 0xffff0000u); }

// ONE cooperative kernel for the whole prep chain. 1024 blocks x 256 threads.
// P0: x col-partials + bf16 cast + deg-zero (blocks 0..511) | Wc partials (512..1023)
// P1: edge atomics->eslot (0..255) | xsum reduce (256..511) | Wc reduce (512..639) | u,v (640)
// P2: CSR scan (block 0) | gsum (blocks 1..32)
__global__ __launch_bounds__(256, 4) void k_prep(
    const float* __restrict__ x, const int* __restrict__ erow,
    const float* __restrict__ W, const float* __restrict__ att_w,
    const float* __restrict__ lin_w,
    float* __restrict__ xpartT, unsigned short* __restrict__ xb,
    int* __restrict__ deg, int* __restrict__ eslot, float* __restrict__ xsum,
    float* __restrict__ part, float* __restrict__ uvpart,
    unsigned short* __restrict__ Wcb, float* __restrict__ Wcf,
    float* __restrict__ u, float* __restrict__ v,
    int* __restrict__ rowstart, float* __restrict__ gsum) {
  cg::grid_group grid = cg::this_grid();
  __shared__ float sred[4];
  __shared__ int wsum[4];
  int b = blockIdx.x, t = threadIdx.x;
  int l = t & 63, w = t >> 6;

  // ---------- P0 ----------
  {
    int gid = b * 256 + t;
    if (gid < NN) deg[gid] = 0;
    if (b < 512) {
      float acc = 0.f;
      int r0 = b * 16;
      for (int r = r0; r < r0 + 16; ++r) {
        float xv = x[r * INC + t];
        acc += xv;
        xb[r * INC + t] = f2bu(xv);
      }
      xpartT[t * 512 + b] = acc;
    } else {
      int bid2 = b - 512;      // 0..511
      int q = bid2 >> 2;       // o-quad 0..127
      int jc = bid2 & 3;
      int j0 = jc * JLEN;
      int o0 = q * 4;
      float a0 = 0.f, a1 = 0.f, a2 = 0.f, a3 = 0.f, su = 0.f, sv = 0.f;
      const float* lw0 = lin_w + (size_t)(o0 + 0) * OUTC + j0;
      const float* lw1 = lin_w + (size_t)(o0 + 1) * OUTC + j0;
      const float* lw2 = lin_w + (size_t)(o0 + 2) * OUTC + j0;
      const float* lw3 = lin_w + (size_t)(o0 + 3) * OUTC + j0;
#pragma unroll 8
      for (int jj = 0; jj < JLEN; ++jj) {
        float wv = W[(j0 + jj) * INC + t];
        a0 = fmaf(lw0[jj], wv, a0);
        a1 = fmaf(lw1[jj], wv, a1);
        a2 = fmaf(lw2[jj], wv, a2);
        a3 = fmaf(lw3[jj], wv, a3);
        if (q == 0) { su = fmaf(att_w[j0 + jj], wv, su); sv += wv; }
      }
      float* pb = part + ((size_t)jc * OUTC + o0) * INC + t;
      pb[0] = a0;
      pb[INC] = a1;
      pb[2 * INC] = a2;
      pb[3 * INC] = a3;
      if (q == 0) {
        uvpart[(jc * 2 + 0) * INC + t] = su;
        uvpart[(jc * 2 + 1) * INC + t] = sv;
      }
    }
  }
  grid.sync();

  // ---------- P1 ----------
  if (b < 256) {
    int e0 = (b * 256 + t) * 4;
    int4 ev = *(const int4*)(erow + e0);
    int4 sl;
    sl.x = atomicAdd(&deg[ev.x], 1);
    sl.y = atomicAdd(&deg[ev.y], 1);
    sl.z = atomicAdd(&deg[ev.z], 1);
    sl.w = atomicAdd(&deg[ev.w], 1);
    *(int4*)(eslot + e0) = sl;
  } else if (b < 512) {
    int k = b - 256;
    float r = xpartT[k * 512 + t] + xpartT[k * 512 + t + 256];
#pragma unroll
    for (int off = 32; off > 0; off >>= 1) r += __shfl_xor(r, off);
    if (l == 0) sred[w] = r;
    __syncthreads();
    if (t == 0) xsum[k] = sred[0] + sred[1] + sred[2] + sred[3];
  } else if (b < 640) {
    int o0 = (b - 512) * 4;
#pragma unroll
    for (int oo = 0; oo < 4; ++oo) {
      float s = 0.f;
#pragma unroll
      for (int jc = 0; jc < JC; ++jc)
        s += part[((size_t)jc * OUTC + o0 + oo) * INC + t];
      Wcb[(size_t)(o0 + oo) * INC + t] = f2bu(s);
      Wcf[(size_t)(o0 + oo) * INC + t] = s;
    }
  } else if (b == 640) {
    float su = 0.f, sv = 0.f;
#pragma unroll
    for (int jc = 0; jc < JC; ++jc) {
      su += uvpart[(jc * 2 + 0) * INC + t];
      sv += uvpart[(jc * 2 + 1) * INC + t];
    }
    u[t] = su;
    v[t] = sv;
  }
  grid.sync();

  // ---------- P2 ----------
  if (b == 0) {
    // exclusive scan deg[8192] -> rowstart[8193]; thread t owns 32 entries
    int base = t * 32;
    int loc[32];
    int s = 0;
#pragma unroll
    for (int j = 0; j < 32; j += 4) {
      int4 d4 = *(const int4*)(deg + base + j);
      loc[j] = s; s += d4.x;
      loc[j + 1] = s; s += d4.y;
      loc[j + 2] = s; s += d4.z;
      loc[j + 3] = s; s += d4.w;
    }
    int inc = s;
#pragma unroll
    for (int off = 1; off < 64; off <<= 1) {
      int up = __shfl_up(inc, off);
      if (l >= off) inc += up;
    }
    if (l == 63) wsum[w] = inc;
    __syncthreads();
    int woff = 0;
#pragma unroll
    for (int q = 0; q < 4; ++q)
      if (q < w) woff += wsum[q];
    int excl = woff + inc - s;
#pragma unroll
    for (int j = 0; j < 32; j += 4) {
      int4 o4;
      o4.x = excl + loc[j];
      o4.y = excl + loc[j + 1];
      o4.z = excl + loc[j + 2];
      o4.w = excl + loc[j + 3];
      *(int4*)(rowstart + base + j) = o4;
    }
    if (t == 255) rowstart[NN] = excl + s;
  } else if (b <= 32) {
    int o0 = (b - 1) * 16;
    for (int oo = 0; oo < 16; ++oo) {
      float r = Wcf[(size_t)(o0 + oo) * INC + t] * xsum[t];
#pragma unroll
      for (int off = 32; off > 0; off >>= 1) r += __shfl_xor(r, off);
      if (l == 0) sred[w] = r;
      __syncthreads();
      if (t == 0) gsum[o0 + oo] = sred[0] + sred[1] + sred[2] + sred[3];
      __syncthreads();
    }
  }
}

// g = x @ Wc.T -> [8192,512] bf16. MFMA 32x32x16, 64x64 block tile, 2x2 waves.
// Epilogue: grid has exactly NE threads -> atomic-free CSR scatter (1 edge each).
__global__ __launch_bounds__(256) void k_gemm3(const unsigned short* __restrict__ xb,
                                               const unsigned short* __restrict__ wb,
                                               unsigned short* __restrict__ g,
                                               const int* __restrict__ erow,
                                               const int* __restrict__ ecol,
                                               const int* __restrict__ eslot,
                                               const int* __restrict__ rowstart,
                                               int* __restrict__ colbuf) {
  int w = threadIdx.x >> 6, l = threadIdx.x & 63;
  int wm = w >> 1, wn = w & 1;
  int r0 = blockIdx.y * 64 + wm * 32;
  int c0 = blockIdx.x * 64 + wn * 32;
  int lr = l & 31;
  int lk = (l >> 5) * 8;
  const unsigned short* pa = xb + (size_t)(r0 + lr) * INC + lk;
  const unsigned short* pb = wb + (size_t)(c0 + lr) * INC + lk;
  f32x16 acc = {};
#pragma unroll
  for (int k0 = 0; k0 < INC; k0 += 16) {
    bf16x8 a = *(const bf16x8*)(pa + k0);
    bf16x8 b = *(const bf16x8*)(pb + k0);
    acc = __builtin_amdgcn_mfma_f32_32x32x16_bf16(a, b, acc, 0, 0, 0);
  }
  // C/D: col = lane&31, row = (reg&3) + 8*(reg>>2) + 4*(lane>>5)
  int col = c0 + lr;
  int rbase = r0 + 4 * (l >> 5);
#pragma unroll
  for (int reg = 0; reg < 16; ++reg) {
    int row = rbase + (reg & 3) + 8 * (reg >> 2);
    g[(size_t)row * OUTC + col] = f2bu(acc[reg]);
  }
  // fused scatter: one edge per thread (1024 blocks * 256 = NE)
  int e = (blockIdx.y * gridDim.x + blockIdx.x) * 256 + threadIdx.x;
  int r = erow[e];
  colbuf[rowstart[r] + eslot[e]] = ecol[e];
}

// FUSED coeff+aggregate: one wave per row.
__global__ __launch_bounds__(256) void k_sagg(const float* __restrict__ x,
                                              const float* __restrict__ u,
                                              const float* __restrict__ v,
                                              const float* __restrict__ gsum,
                                              const unsigned short* __restrict__ g,
                                              const int* __restrict__ rowstart,
                                              const int* __restrict__ colbuf,
                                              float* __restrict__ out) {
  __shared__ int scols[4][MAXD];
  __shared__ float scoef[4][MAXD];
  int w = threadIdx.x >> 6, l = threadIdx.x & 63;
  int i = blockIdx.x * 4 + w;

  // alpha_i = leaky_relu((x_i.u)*(x_i.v))
  float su = 0.f, sv = 0.f;
#pragma unroll
  for (int kk = 0; kk < 4; ++kk) {
    int k = l + kk * 64;
    float xv = x[(size_t)i * INC + k];
    su = fmaf(xv, u[k], su);
    sv = fmaf(xv, v[k], sv);
  }
#pragma unroll
  for (int off = 32; off > 0; off >>= 1) {
    su += __shfl_xor(su, off);
    sv += __shfl_xor(sv, off);
  }
  float a = su * sv;
  float al = a > 0.f ? a : 0.2f * a;

  int s = rowstart[i];
  int d = rowstart[i + 1] - s;
  if (d > MAXD) d = MAXD;
  if (l < d) scols[w][l] = colbuf[s + l];
  int l2 = l + 64;
  if (l2 < d) scols[w][l2] = colbuf[s + l2];
  __syncthreads();
  int c0s = -1, c1s = -2;
  if (l < d) c0s = scols[w][l];
  if (l2 < d) c1s = scols[w][l2];
  int m0 = 0, m1 = 0, f0 = 1, f1 = 1;
  for (int q = 0; q < d; ++q) {
    int cq = scols[w][q];
    if (cq == c0s) { m0++; if (q < l) f0 = 0; }
    if (cq == c1s) { m1++; if (q < l2) f1 = 0; }
  }
  int mm = m0 > m1 ? m0 : m1;
#pragma unroll
  for (int off = 32; off > 0; off >>= 1) {
    int b = __shfl_xor(mm, off);
    if (b > mm) mm = b;
  }
  float M = (al > 0.f) ? al * (float)mm : 0.f;
  float eMn = expf(-M);
  float se = 0.f;
  int nc = 0;
  float cf0 = 0.f, cf1 = 0.f;
  if (l < d && f0) {
    float e0 = expf(al * (float)m0 - M);
    se += e0; nc++; cf0 = e0 - eMn;
  }
  if (l2 < d && f1) {
    float e1 = expf(al * (float)m1 - M);
    se += e1; nc++; cf1 = e1 - eMn;
  }
#pragma unroll
  for (int off = 32; off > 0; off >>= 1) {
    se += __shfl_xor(se, off);
    nc += __shfl_xor(nc, off);
  }
  float Z = (float)(NN - nc) * eMn + se;
  float invZ = 1.0f / Z;
  if (l < d) scoef[w][l] = cf0 * invZ;
  if (l2 < d) scoef[w][l2] = cf1 * invZ;
  float rs = eMn * invZ;

  // Phase B: gather. lane owns channels [8l, 8l+8); 2-way unrolled.
  int c0 = l * 8;
  float acc[8];
  float4 gs0 = *(const float4*)(gsum + c0);
  float4 gs1 = *(const float4*)(gsum + c0 + 4);
  acc[0] = rs * gs0.x; acc[1] = rs * gs0.y; acc[2] = rs * gs0.z; acc[3] = rs * gs0.w;
  acc[4] = rs * gs1.x; acc[5] = rs * gs1.y; acc[6] = rs * gs1.z; acc[7] = rs * gs1.w;
  int k = 0;
  for (; k + 2 <= d; k += 2) {
    int ca = scols[w][k], cb = scols[w][k + 1];
    float fa = scoef[w][k], fb = scoef[w][k + 1];
    uint4 pva = *(const uint4*)(g + (size_t)ca * OUTC + c0);
    uint4 pvb = *(const uint4*)(g + (size_t)cb * OUTC + c0);
    acc[0] = fmaf(fa, blo(pva.x), fmaf(fb, blo(pvb.x), acc[0]));
    acc[1] = fmaf(fa, bhi(pva.x), fmaf(fb, bhi(pvb.x), acc[1]));
    acc[2] = fmaf(fa, blo(pva.y), fmaf(fb, blo(pvb.y), acc[2]));
    acc[3] = fmaf(fa, bhi(pva.y), fmaf(fb, bhi(pvb.y), acc[3]));
    acc[4] = fmaf(fa, blo(pva.z), fmaf(fb, blo(pvb.z), acc[4]));
    acc[5] = fmaf(fa, bhi(pva.z), fmaf(fb, bhi(pvb.z), acc[5]));
    acc[6] = fmaf(fa, blo(pva.w), fmaf(fb, blo(pvb.w), acc[6]));
    acc[7] = fmaf(fa, bhi(pva.w), fmaf(fb, bhi(pvb.w), acc[7]));
  }
  if (k < d) {
    int ca = scols[w][k];
    float fa = scoef[w][k];
    uint4 pva = *(const uint4*)(g + (size_t)ca * OUTC + c0);
    acc[0] = fmaf(fa, blo(pva.x), acc[0]);
    acc[1] = fmaf(fa, bhi(pva.x), acc[1]);
    acc[2] = fmaf(fa, blo(pva.y), acc[2]);
    acc[3] = fmaf(fa, bhi(pva.y), acc[3]);
    acc[4] = fmaf(fa, blo(pva.z), acc[4]);
    acc[5] = fmaf(fa, bhi(pva.z), acc[5]);
    acc[6] = fmaf(fa, blo(pva.w), acc[6]);
    acc[7] = fmaf(fa, bhi(pva.w), acc[7]);
  }
  float4 o0, o1;
  o0.x = acc[0] > 0.f ? acc[0] : expm1f(acc[0]);
  o0.y = acc[1] > 0.f ? acc[1] : expm1f(acc[1]);
  o0.z = acc[2] > 0.f ? acc[2] : expm1f(acc[2]);
  o0.w = acc[3] > 0.f ? acc[3] : expm1f(acc[3]);
  o1.x = acc[4] > 0.f ? acc[4] : expm1f(acc[4]);
  o1.y = acc[5] > 0.f ? acc[5] : expm1f(acc[5]);
  o1.z = acc[6] > 0.f ? acc[6] : expm1f(acc[6]);
  o1.w = acc[7] > 0.f ? acc[7] : expm1f(acc[7]);
  float* po = out + (size_t)i * OUTC + c0;
  *(float4*)po = o0;
  *(float4*)(po + 4) = o1;
}

extern "C" void kernel_launch(void* const* d_in, const int* in_sizes, int n_in,
                              void* d_out, int out_size, void* d_ws, size_t ws_size,
                              hipStream_t stream) {
  const float* x = (const float*)d_in[0];
  const int* ei = (const int*)d_in[1];
  const float* W = (const float*)d_in[2];
  const float* att_w = (const float*)d_in[3];
  const float* lin_w = (const float*)d_in[4];
  float* out = (float*)d_out;
  const int* erow = ei;
  const int* ecol = ei + NE;

  char* ws = (char*)d_ws;
  size_t off = 0;
  auto alloc = [&](size_t bytes) {
    void* p = ws + off;
    off = (off + bytes + 255) & ~(size_t)255;
    return p;
  };
  float* u = (float*)alloc(INC * 4);
  float* v = (float*)alloc(INC * 4);
  float* xsum = (float*)alloc(INC * 4);
  float* xpartT = (float*)alloc((size_t)INC * 512 * 4);
  float* gsum = (float*)alloc(OUTC * 4);
  float* part = (float*)alloc((size_t)JC * OUTC * INC * 4);
  float* uvpart = (float*)alloc(JC * 2 * INC * 4);
  unsigned short* Wcb = (unsigned short*)alloc((size_t)OUTC * INC * 2);
  float* Wcf = (float*)alloc((size_t)OUTC * INC * 4);
  unsigned short* xb = (unsigned short*)alloc((size_t)NN * INC * 2);
  unsigned short* g = (unsigned short*)alloc((size_t)NN * OUTC * 2);
  int* deg = (int*)alloc(NN * 4);
  int* rowstart = (int*)alloc((NN + 1) * 4);
  int* eslot = (int*)alloc(NE * 4);
  int* colbuf = (int*)alloc(NE * 4);
  (void)ws_size; (void)in_sizes; (void)n_in; (void)out_size;

  void* args[] = {(void*)&x,      (void*)&erow,  (void*)&W,    (void*)&att_w,
                  (void*)&lin_w,  (void*)&xpartT, (void*)&xb,  (void*)&deg,
                  (void*)&eslot,  (void*)&xsum,  (void*)&part, (void*)&uvpart,
                  (void*)&Wcb,    (void*)&Wcf,   (void*)&u,    (void*)&v,
                  (void*)&rowstart, (void*)&gsum};
  hipLaunchCooperativeKernel((void*)k_prep, dim3(1024), dim3(256), args, 0, stream);
  k_gemm3<<<dim3(OUTC / 64, NN / 64), 256, 0, stream>>>(xb, Wcb, g, erow, ecol, eslot, rowstart, colbuf);
  k_sagg<<<NN / 4, 256, 0, stream>>>(x, u, v, gsum, g, rowstart, colbuf, out);
}

// Round 11
// 84.155 us; speedup vs baseline: 3.7561x; 3.7561x over previous
//
#include <hip/hip_runtime.h>
#include <hip/hip_bf16.h>

#define NN 8192
#define INC 256
#define OUTC 512
#define NE 262144
#define MAXD 128
#define JC 8
#define JLEN 64  // OUTC / JC

typedef __hip_bfloat16 bf16;
typedef short bf16x8 __attribute__((ext_vector_type(8)));
typedef float f32x16 __attribute__((ext_vector_type(16)));

__device__ inline unsigned short f2bu(float f) {
  __hip_bfloat16 b = __float2bfloat16(f);
  return *reinterpret_cast<unsigned short*>(&b);
}
__device__ inline float blo(unsigned int x) { return __uint_as_float(x << 16); }
__device__ inline float bhi(unsigned int x) { return __uint_as_float(x & 0xffff0000u); }

// P0 merged: blocks 0..255 = x col-partials + bf16 cast + deg zero;
// blocks 256..1279 = Wc j-chunk partials (+ u,v partials on o-quad 0).
__global__ __launch_bounds__(256) void k_p0(const float* __restrict__ x,
                                            const float* __restrict__ W,
                                            const float* __restrict__ att_w,
                                            const float* __restrict__ lin_w,
                                            float* __restrict__ xpartT,
                                            unsigned short* __restrict__ xb,
                                            int* __restrict__ deg,
                                            float* __restrict__ part,
                                            float* __restrict__ uvpart) {
  int b = blockIdx.x, t = threadIdx.x;
  if (b < 256) {
    int gid = b * 256 + t;
    if (gid < NN) deg[gid] = 0;
    float acc = 0.f;
    int r0 = b * (NN / 256);
    for (int r = r0; r < r0 + NN / 256; ++r) {
      float xv = x[r * INC + t];
      acc += xv;
      xb[r * INC + t] = f2bu(xv);
    }
    xpartT[t * 256 + b] = acc;
    return;
  }
  int bid2 = b - 256;      // 0..1023
  int q = bid2 >> 3;       // o-quad 0..127
  int jc = bid2 & 7;
  int j0 = jc * JLEN;
  int o0 = q * 4;
  float a0 = 0.f, a1 = 0.f, a2 = 0.f, a3 = 0.f, su = 0.f, sv = 0.f;
  const float* lw0 = lin_w + (size_t)(o0 + 0) * OUTC + j0;
  const float* lw1 = lin_w + (size_t)(o0 + 1) * OUTC + j0;
  const float* lw2 = lin_w + (size_t)(o0 + 2) * OUTC + j0;
  const float* lw3 = lin_w + (size_t)(o0 + 3) * OUTC + j0;
#pragma unroll 8
  for (int jj = 0; jj < JLEN; ++jj) {
    float wv = W[(j0 + jj) * INC + t];
    a0 = fmaf(lw0[jj], wv, a0);
    a1 = fmaf(lw1[jj], wv, a1);
    a2 = fmaf(lw2[jj], wv, a2);
    a3 = fmaf(lw3[jj], wv, a3);
    if (q == 0) { su = fmaf(att_w[j0 + jj], wv, su); sv += wv; }
  }
  float* pb = part + ((size_t)jc * OUTC + o0) * INC + t;
  pb[0] = a0;
  pb[INC] = a1;
  pb[2 * INC] = a2;
  pb[3 * INC] = a3;
  if (q == 0) {
    uvpart[(jc * 2 + 0) * INC + t] = su;
    uvpart[(jc * 2 + 1) * INC + t] = sv;
  }
}

// P1: 256 blocks: block k reduces xpartT[k][0..255]; fused edge-degree atomics
// whose return value IS the edge's slot within its row (-> eslot).
__global__ __launch_bounds__(256) void k_p1(const float* __restrict__ xpartT,
                                            float* __restrict__ xsum,
                                            const int* __restrict__ erow,
                                            int* __restrict__ deg,
                                            int* __restrict__ eslot) {
  __shared__ float sred[4];
  int k = blockIdx.x, t = threadIdx.x;
  int l = t & 63, w = t >> 6;
  float r = xpartT[k * 256 + t];
#pragma unroll
  for (int off = 32; off > 0; off >>= 1) r += __shfl_xor(r, off);
  if (l == 0) sred[w] = r;
  // degree atomics: 65536 threads x 4 edges; atomic return = slot
  int e0 = (k * 256 + t) * 4;
  int4 ev = *(const int4*)(erow + e0);
  int4 sl;
  sl.x = atomicAdd(&deg[ev.x], 1);
  sl.y = atomicAdd(&deg[ev.y], 1);
  sl.z = atomicAdd(&deg[ev.z], 1);
  sl.w = atomicAdd(&deg[ev.w], 1);
  *(int4*)(eslot + e0) = sl;
  __syncthreads();
  if (t == 0) xsum[k] = sred[0] + sred[1] + sred[2] + sred[3];
}

// P2: blocks 0..127 reduce Wc partials -> Wcb bf16, gsum (block 0: u,v).
// Block 128: shfl-based exclusive scan deg[8192] -> rowstart[8193].
__global__ __launch_bounds__(256) void k_p2(const float* __restrict__ part,
                                            const float* __restrict__ uvpart,
                                            const float* __restrict__ xsum,
                                            unsigned short* __restrict__ Wcb,
                                            float* __restrict__ gsum,
                                            float* __restrict__ u,
                                            float* __restrict__ v,
                                            const int* __restrict__ deg,
                                            int* __restrict__ rowstart) {
  __shared__ float sred[4][4];
  __shared__ int wsum[4];
  int k = threadIdx.x;
  int l = k & 63, w = k >> 6;

  if (blockIdx.x == 128) {
    // exclusive scan: thread k owns deg[32k .. 32k+32)
    int base = k * 32;
    int loc[32];
    int s = 0;
#pragma unroll
    for (int j = 0; j < 32; j += 4) {
      int4 d4 = *(const int4*)(deg + base + j);
      loc[j] = s; s += d4.x;
      loc[j + 1] = s; s += d4.y;
      loc[j + 2] = s; s += d4.z;
      loc[j + 3] = s; s += d4.w;
    }
    int inc = s;
#pragma unroll
    for (int off = 1; off < 64; off <<= 1) {
      int up = __shfl_up(inc, off);
      if (l >= off) inc += up;
    }
    if (l == 63) wsum[w] = inc;
    __syncthreads();
    int woff = 0;
#pragma unroll
    for (int q = 0; q < 4; ++q)
      if (q < w) woff += wsum[q];
    int excl = woff + inc - s;
#pragma unroll
    for (int j = 0; j < 32; j += 4) {
      int4 o4;
      o4.x = excl + loc[j];
      o4.y = excl + loc[j + 1];
      o4.z = excl + loc[j + 2];
      o4.w = excl + loc[j + 3];
      *(int4*)(rowstart + base + j) = o4;
    }
    if (k == 255) rowstart[NN] = excl + s;
    return;
  }

  int o0 = blockIdx.x * 4;
#pragma unroll
  for (int oo = 0; oo < 4; ++oo) {
    float s = 0.f;
#pragma unroll
    for (int jc = 0; jc < JC; ++jc)
      s += part[((size_t)jc * OUTC + o0 + oo) * INC + k];
    Wcb[(size_t)(o0 + oo) * INC + k] = f2bu(s);
    float r = s * xsum[k];
#pragma unroll
    for (int off = 32; off > 0; off >>= 1) r += __shfl_xor(r, off);
    if (l == 0) sred[oo][w] = r;
  }
  __syncthreads();
  if (k < 4) gsum[o0 + k] = sred[k][0] + sred[k][1] + sred[k][2] + sred[k][3];
  if (blockIdx.x == 0) {
    float su = 0.f, sv = 0.f;
#pragma unroll
    for (int jc = 0; jc < JC; ++jc) {
      su += uvpart[(jc * 2 + 0) * INC + k];
      sv += uvpart[(jc * 2 + 1) * INC + k];
    }
    u[k] = su;
    v[k] = sv;
  }
}

// g = x @ Wc.T -> [8192,512] bf16. MFMA 32x32x16, 64x64 block tile, 2x2 waves.
// Epilogue: grid has exactly NE threads -> atomic-free CSR scatter (1 edge each).
__global__ __launch_bounds__(256) void k_gemm3(const unsigned short* __restrict__ xb,
                                               const unsigned short* __restrict__ wb,
                                               unsigned short* __restrict__ g,
                                               const int* __restrict__ erow,
                                               const int* __restrict__ ecol,
                                               const int* __restrict__ eslot,
                                               const int* __restrict__ rowstart,
                                               int* __restrict__ colbuf) {
  int w = threadIdx.x >> 6, l = threadIdx.x & 63;
  int wm = w >> 1, wn = w & 1;
  int r0 = blockIdx.y * 64 + wm * 32;
  int c0 = blockIdx.x * 64 + wn * 32;
  int lr = l & 31;
  int lk = (l >> 5) * 8;
  const unsigned short* pa = xb + (size_t)(r0 + lr) * INC + lk;
  const unsigned short* pb = wb + (size_t)(c0 + lr) * INC + lk;
  f32x16 acc = {};
#pragma unroll
  for (int k0 = 0; k0 < INC; k0 += 16) {
    bf16x8 a = *(const bf16x8*)(pa + k0);
    bf16x8 b = *(const bf16x8*)(pb + k0);
    acc = __builtin_amdgcn_mfma_f32_32x32x16_bf16(a, b, acc, 0, 0, 0);
  }
  // C/D: col = lane&31, row = (reg&3) + 8*(reg>>2) + 4*(lane>>5)
  int col = c0 + lr;
  int rbase = r0 + 4 * (l >> 5);
#pragma unroll
  for (int reg = 0; reg < 16; ++reg) {
    int row = rbase + (reg & 3) + 8 * (reg >> 2);
    g[(size_t)row * OUTC + col] = f2bu(acc[reg]);
  }
  // fused scatter: one edge per thread (1024 blocks * 256 = NE)
  int e = (blockIdx.y * gridDim.x + blockIdx.x) * 256 + threadIdx.x;
  int r = erow[e];
  colbuf[rowstart[r] + eslot[e]] = ecol[e];
}

// FUSED coeff+aggregate: one wave per row.
__global__ __launch_bounds__(256) void k_sagg(const float* __restrict__ x,
                                              const float* __restrict__ u,
                                              const float* __restrict__ v,
                                              const float* __restrict__ gsum,
                                              const unsigned short* __restrict__ g,
                                              const int* __restrict__ rowstart,
                                              const int* __restrict__ colbuf,
                                              float* __restrict__ out) {
  __shared__ int scols[4][MAXD];
  __shared__ float scoef[4][MAXD];
  int w = threadIdx.x >> 6, l = threadIdx.x & 63;
  int i = blockIdx.x * 4 + w;

  // alpha_i = leaky_relu((x_i.u)*(x_i.v))
  float su = 0.f, sv = 0.f;
#pragma unroll
  for (int kk = 0; kk < 4; ++kk) {
    int k = l + kk * 64;
    float xv = x[(size_t)i * INC + k];
    su = fmaf(xv, u[k], su);
    sv = fmaf(xv, v[k], sv);
  }
#pragma unroll
  for (int off = 32; off > 0; off >>= 1) {
    su += __shfl_xor(su, off);
    sv += __shfl_xor(sv, off);
  }
  float a = su * sv;
  float al = a > 0.f ? a : 0.2f * a;

  int s = rowstart[i];
  int d = rowstart[i + 1] - s;
  if (d > MAXD) d = MAXD;
  if (l < d) scols[w][l] = colbuf[s + l];
  int l2 = l + 64;
  if (l2 < d) scols[w][l2] = colbuf[s + l2];
  __syncthreads();
  int c0s = -1, c1s = -2;
  if (l < d) c0s = scols[w][l];
  if (l2 < d) c1s = scols[w][l2];
  int m0 = 0, m1 = 0, f0 = 1, f1 = 1;
  for (int q = 0; q < d; ++q) {
    int cq = scols[w][q];
    if (cq == c0s) { m0++; if (q < l) f0 = 0; }
    if (cq == c1s) { m1++; if (q < l2) f1 = 0; }
  }
  int mm = m0 > m1 ? m0 : m1;
#pragma unroll
  for (int off = 32; off > 0; off >>= 1) {
    int b = __shfl_xor(mm, off);
    if (b > mm) mm = b;
  }
  float M = (al > 0.f) ? al * (float)mm : 0.f;
  float eMn = expf(-M);
  float se = 0.f;
  int nc = 0;
  float cf0 = 0.f, cf1 = 0.f;
  if (l < d && f0) {
    float e0 = expf(al * (float)m0 - M);
    se += e0; nc++; cf0 = e0 - eMn;
  }
  if (l2 < d && f1) {
    float e1 = expf(al * (float)m1 - M);
    se += e1; nc++; cf1 = e1 - eMn;
  }
#pragma unroll
  for (int off = 32; off > 0; off >>= 1) {
    se += __shfl_xor(se, off);
    nc += __shfl_xor(nc, off);
  }
  float Z = (float)(NN - nc) * eMn + se;
  float invZ = 1.0f / Z;
  if (l < d) scoef[w][l] = cf0 * invZ;
  if (l2 < d) scoef[w][l2] = cf1 * invZ;
  float rs = eMn * invZ;

  // Phase B: gather. lane owns channels [8l, 8l+8); 2-way unrolled.
  int c0 = l * 8;
  float acc[8];
  float4 gs0 = *(const float4*)(gsum + c0);
  float4 gs1 = *(const float4*)(gsum + c0 + 4);
  acc[0] = rs * gs0.x; acc[1] = rs * gs0.y; acc[2] = rs * gs0.z; acc[3] = rs * gs0.w;
  acc[4] = rs * gs1.x; acc[5] = rs * gs1.y; acc[6] = rs * gs1.z; acc[7] = rs * gs1.w;
  int k = 0;
  for (; k + 2 <= d; k += 2) {
    int ca = scols[w][k], cb = scols[w][k + 1];
    float fa = scoef[w][k], fb = scoef[w][k + 1];
    uint4 pva = *(const uint4*)(g + (size_t)ca * OUTC + c0);
    uint4 pvb = *(const uint4*)(g + (size_t)cb * OUTC + c0);
    acc[0] = fmaf(fa, blo(pva.x), fmaf(fb, blo(pvb.x), acc[0]));
    acc[1] = fmaf(fa, bhi(pva.x), fmaf(fb, bhi(pvb.x), acc[1]));
    acc[2] = fmaf(fa, blo(pva.y), fmaf(fb, blo(pvb.y), acc[2]));
    acc[3] = fmaf(fa, bhi(pva.y), fmaf(fb, bhi(pvb.y), acc[3]));
    acc[4] = fmaf(fa, blo(pva.z), fmaf(fb, blo(pvb.z), acc[4]));
    acc[5] = fmaf(fa, bhi(pva.z), fmaf(fb, bhi(pvb.z), acc[5]));
    acc[6] = fmaf(fa, blo(pva.w), fmaf(fb, blo(pvb.w), acc[6]));
    acc[7] = fmaf(fa, bhi(pva.w), fmaf(fb, bhi(pvb.w), acc[7]));
  }
  if (k < d) {
    int ca = scols[w][k];
    float fa = scoef[w][k];
    uint4 pva = *(const uint4*)(g + (size_t)ca * OUTC + c0);
    acc[0] = fmaf(fa, blo(pva.x), acc[0]);
    acc[1] = fmaf(fa, bhi(pva.x), acc[1]);
    acc[2] = fmaf(fa, blo(pva.y), acc[2]);
    acc[3] = fmaf(fa, bhi(pva.y), acc[3]);
    acc[4] = fmaf(fa, blo(pva.z), acc[4]);
    acc[5] = fmaf(fa, bhi(pva.z), acc[5]);
    acc[6] = fmaf(fa, blo(pva.w), acc[6]);
    acc[7] = fmaf(fa, bhi(pva.w), acc[7]);
  }
  float4 o0, o1;
  o0.x = acc[0] > 0.f ? acc[0] : expm1f(acc[0]);
  o0.y = acc[1] > 0.f ? acc[1] : expm1f(acc[1]);
  o0.z = acc[2] > 0.f ? acc[2] : expm1f(acc[2]);
  o0.w = acc[3] > 0.f ? acc[3] : expm1f(acc[3]);
  o1.x = acc[4] > 0.f ? acc[4] : expm1f(acc[4]);
  o1.y = acc[5] > 0.f ? acc[5] : expm1f(acc[5]);
  o1.z = acc[6] > 0.f ? acc[6] : expm1f(acc[6]);
  o1.w = acc[7] > 0.f ? acc[7] : expm1f(acc[7]);
  float* po = out + (size_t)i * OUTC + c0;
  *(float4*)po = o0;
  *(float4*)(po + 4) = o1;
}

extern "C" void kernel_launch(void* const* d_in, const int* in_sizes, int n_in,
                              void* d_out, int out_size, void* d_ws, size_t ws_size,
                              hipStream_t stream) {
  const float* x = (const float*)d_in[0];
  const int* ei = (const int*)d_in[1];
  const float* W = (const float*)d_in[2];
  const float* att_w = (const float*)d_in[3];
  const float* lin_w = (const float*)d_in[4];
  float* out = (float*)d_out;
  const int* erow = ei;
  const int* ecol = ei + NE;

  char* ws = (char*)d_ws;
  size_t off = 0;
  auto alloc = [&](size_t bytes) {
    void* p = ws + off;
    off = (off + bytes + 255) & ~(size_t)255;
    return p;
  };
  float* u = (float*)alloc(INC * 4);
  float* v = (float*)alloc(INC * 4);
  float* xsum = (float*)alloc(INC * 4);
  float* xpartT = (float*)alloc(INC * 256 * 4);
  float* gsum = (float*)alloc(OUTC * 4);
  float* part = (float*)alloc((size_t)JC * OUTC * INC * 4);
  float* uvpart = (float*)alloc(JC * 2 * INC * 4);
  unsigned short* Wcb = (unsigned short*)alloc((size_t)OUTC * INC * 2);
  unsigned short* xb = (unsigned short*)alloc((size_t)NN * INC * 2);
  unsigned short* g = (unsigned short*)alloc((size_t)NN * OUTC * 2);
  int* deg = (int*)alloc(NN * 4);
  int* rowstart = (int*)alloc((NN + 1) * 4);
  int* eslot = (int*)alloc(NE * 4);
  int* colbuf = (int*)alloc(NE * 4);
  (void)ws_size; (void)in_sizes; (void)n_in; (void)out_size;

  k_p0<<<256 + 1024, 256, 0, stream>>>(x, W, att_w, lin_w, xpartT, xb, deg, part, uvpart);
  k_p1<<<INC, 256, 0, stream>>>(xpartT, xsum, erow, deg, eslot);
  k_p2<<<OUTC / 4 + 1, 256, 0, stream>>>(part, uvpart, xsum, Wcb, gsum, u, v, deg, rowstart);
  k_gemm3<<<dim3(OUTC / 64, NN / 64), 256, 0, stream>>>(xb, Wcb, g, erow, ecol, eslot, rowstart, colbuf);
  k_sagg<<<NN / 4, 256, 0, stream>>>(x, u, v, gsum, g, rowstart, colbuf, out);
}